// Round 14
// baseline (1879.702 us; speedup 1.0000x reference)
//
#include <hip/hip_runtime.h>
#include <hip/hip_bf16.h>
#include <math.h>
#include <stdint.h>

using bf16 = __hip_bfloat16;
typedef __attribute__((ext_vector_type(8))) short short8;   // 8 bf16
typedef __attribute__((ext_vector_type(4))) float floatx4;  // MFMA C/D frag (f32)
typedef __attribute__((ext_vector_type(4))) int int4v;      // i8 K=64 frag / i32 acc

typedef const __attribute__((address_space(1))) void* gptr_t;
typedef __attribute__((address_space(3))) void* lptr_t;

__device__ __forceinline__ void load_lds16(const void* g, void* l) {
    __builtin_amdgcn_global_load_lds((gptr_t)(uintptr_t)g, (lptr_t)(uintptr_t)l, 16, 0, 0);
}

// wait until at most N vector-memory ops outstanding. gfx9 vmcnt 6 bits:
// lo[3:0]=bits3:0, hi[5:4]=bits15:14; lgkm/exp left at max (no wait).
#define WAIT_VM(n) __builtin_amdgcn_s_waitcnt(0x0F70 | ((n) & 15) | (((n) >> 4) << 14))

// tanh(x) = 1 - 2/(exp(2x)+1)
__device__ __forceinline__ float fast_tanh(float x) {
    float e = __expf(2.f * x);
    return 1.f - 2.f / (e + 1.f);
}

__device__ __forceinline__ int8_t q_i8(float x, float inv127S) {
    int v = __float2int_rn(x * inv127S);
    v = v > 127 ? 127 : (v < -127 ? -127 : v);
    return (int8_t)v;
}

// device-scope atomic max for positive floats (int ordering preserves)
__device__ __forceinline__ void atomicMaxPosF(float* p, float v) {
    atomicMax(reinterpret_cast<int*>(p), __float_as_int(v));
}

// ---------------------------------------------------------------------------
// R14 = R13 (verified 1771us, absmax 0.078) + i8 L1 (the last bf16 GEMM).
// x0 is unbounded -> per-tensor dynamic scale S = hmax + 1.0 tracked at
// runtime: hmax_kern/prep seed it; mode-2 epilogues atomicMax |h'| into a
// pending slot; each L1's block 0 commits pend->cur (stream-ordered,
// cross-dispatch visibility is standard HIP kernel-boundary semantics).
// Every x0 writer publishes its S in slots[2]; the next L1 dequantizes with
// it. W1 gets the verified per-row i8 quant. Bounds: |alpha*kv|<=0.36,
// |te|<=0.45, per-step drift <=0.4 -> S covers; outliers clamped.
// Noise is per-eval (no accumulation, unlike R11's RMW drift): est final
// absmax 0.09-0.13 < 0.152. L1 core = verified gemm_tanh_i8 pattern, K=512.
// slots[0]=hmax_cur, slots[1]=hmax_pend, slots[2]=xscale.
// ---------------------------------------------------------------------------

// L1: x1q = i8(tanh(acc*dq1[n]*S + b1)*127), i8 core. K=512, N=1024.
template <int K, int N>
__global__ void __launch_bounds__(256, 2)
gemm_l1(const int8_t* __restrict__ A, const int8_t* __restrict__ W,
        const float* __restrict__ dq, const float* __restrict__ bias,
        int8_t* __restrict__ out, float* __restrict__ slots) {
    constexpr int MT = 4, NT = 4;
    constexpr int nIter = K / 128;   // 4
    __shared__ alignas(16) int8_t lA[2][128 * 128];
    __shared__ alignas(16) int8_t lB[2][128 * 128];

    const int b   = blockIdx.x + gridDim.x * blockIdx.y;   // grid (8, 64)
    const int xcd = b & 7, j = b >> 3;
    const int bx  = j & 7;
    const int by  = xcd + 8 * (j >> 3);

    const int tid  = threadIdx.x;

    // commit pending hmax (written by the previous mode-2 dispatch) for this
    // step's gemm_k dispatches. Only slots[0]/[1] touched; no L1 block reads
    // them, so no intra-dispatch race.
    if (b == 0 && tid == 0) {
        const float p = slots[1];
        if (p > 0.f) { slots[0] = p; slots[1] = 0.f; }
    }
    const float xs = slots[2];   // scale used by this x0's writer

    const int lane = tid & 63;
    const int w    = tid >> 6;
    const int wr   = w >> 1, wc = w & 1;
    const int quad = lane >> 4, l16 = lane & 15;
    const int brow = by * 128;
    const int bcol = bx * 128;

    const int8_t* gA[4]; const int8_t* gW[4]; int lq[4];
#pragma unroll
    for (int jj = 0; jj < 4; ++jj) {
        const int q = tid + jj * 256;
        const int r = q >> 3, s = (q & 7) ^ (r & 7);
        gA[jj] = A + (size_t)(brow + r) * K + s * 16;
        gW[jj] = W + (size_t)(bcol + r) * K + s * 16;
        lq[jj] = q * 16;
    }

    int4v acc[MT][NT];
    const int4v izero = {0, 0, 0, 0};
#pragma unroll
    for (int mt = 0; mt < MT; ++mt)
#pragma unroll
        for (int nt = 0; nt < NT; ++nt) acc[mt][nt] = izero;

    const int arow0 = wr * 64 + l16;
    const int brow0 = wc * 64 + l16;
    const int x7 = l16 & 7;

#pragma unroll
    for (int jj = 0; jj < 4; ++jj) load_lds16(gA[jj], &lA[0][0] + lq[jj]);
#pragma unroll
    for (int jj = 0; jj < 4; ++jj) load_lds16(gW[jj], &lB[0][0] + lq[jj]);

#pragma unroll
    for (int kt = 0; kt < nIter; ++kt) {
        const int cur = kt & 1;
        if (kt + 1 < nIter) {
#pragma unroll
            for (int jj = 0; jj < 4; ++jj)
                load_lds16(gA[jj] + (kt + 1) * 128, &lA[cur ^ 1][0] + lq[jj]);
#pragma unroll
            for (int jj = 0; jj < 4; ++jj)
                load_lds16(gW[jj] + (kt + 1) * 128, &lB[cur ^ 1][0] + lq[jj]);
            WAIT_VM(8);
        } else {
            WAIT_VM(0);
        }
        __builtin_amdgcn_s_barrier();

#pragma unroll
        for (int kk = 0; kk < 2; ++kk) {
            const int sw = ((kk * 4 + quad) ^ x7) * 16;
            int4v af[MT], bfr[NT];
#pragma unroll
            for (int mt = 0; mt < MT; ++mt)
                af[mt] = *(const int4v*)(&lA[cur][(arow0 + mt * 16) * 128 + sw]);
#pragma unroll
            for (int nt = 0; nt < NT; ++nt)
                bfr[nt] = *(const int4v*)(&lB[cur][(brow0 + nt * 16) * 128 + sw]);
#pragma unroll
            for (int mt = 0; mt < MT; ++mt)
#pragma unroll
                for (int nt = 0; nt < NT; ++nt)
                    acc[mt][nt] = __builtin_amdgcn_mfma_i32_16x16x64_i8(
                        af[mt], bfr[nt], acc[mt][nt], 0, 0, 0);
        }
        __builtin_amdgcn_s_barrier();
    }

    const int m0 = brow + wr * 64 + quad * 4;
    const int n0 = bcol + wc * 64 + l16;
#pragma unroll
    for (int mt = 0; mt < MT; ++mt)
#pragma unroll
        for (int nt = 0; nt < NT; ++nt) {
            const int n = n0 + nt * 16;
            const float bb = bias[n];
            const float dqs = dq[n] * xs;
#pragma unroll
            for (int i = 0; i < 4; ++i) {
                const int m = m0 + mt * 16 + i;
                const float t = fast_tanh((float)acc[mt][nt][i] * dqs + bb);
                out[(size_t)m * N + n] = (int8_t)__float2int_rn(t * 127.f);
            }
        }
}

// L2: x2i = i8(tanh(acc*dq[n] + b2)*127), i8 core. 128x128, dbuf, 2 blk/CU.
template <int K, int N>
__global__ void __launch_bounds__(256, 2)
gemm_tanh_i8(const int8_t* __restrict__ A, const int8_t* __restrict__ W,
             const float* __restrict__ dq, const float* __restrict__ bias,
             int8_t* __restrict__ out) {
    constexpr int MT = 4, NT = 4;
    constexpr int nIter = K / 128;
    __shared__ alignas(16) int8_t lA[2][128 * 128];
    __shared__ alignas(16) int8_t lB[2][128 * 128];

    const int b   = blockIdx.x + gridDim.x * blockIdx.y;   // grid (8, 64)
    const int xcd = b & 7, j = b >> 3;
    const int bx  = j & 7;
    const int by  = xcd + 8 * (j >> 3);

    const int tid  = threadIdx.x;
    const int lane = tid & 63;
    const int w    = tid >> 6;
    const int wr   = w >> 1, wc = w & 1;
    const int quad = lane >> 4, l16 = lane & 15;
    const int brow = by * 128;
    const int bcol = bx * 128;

    const int8_t* gA[4]; const int8_t* gW[4]; int lq[4];
#pragma unroll
    for (int jj = 0; jj < 4; ++jj) {
        const int q = tid + jj * 256;
        const int r = q >> 3, s = (q & 7) ^ (r & 7);
        gA[jj] = A + (size_t)(brow + r) * K + s * 16;
        gW[jj] = W + (size_t)(bcol + r) * K + s * 16;
        lq[jj] = q * 16;
    }

    int4v acc[MT][NT];
    const int4v izero = {0, 0, 0, 0};
#pragma unroll
    for (int mt = 0; mt < MT; ++mt)
#pragma unroll
        for (int nt = 0; nt < NT; ++nt) acc[mt][nt] = izero;

    const int arow0 = wr * 64 + l16;
    const int brow0 = wc * 64 + l16;
    const int x7 = l16 & 7;

#pragma unroll
    for (int jj = 0; jj < 4; ++jj) load_lds16(gA[jj], &lA[0][0] + lq[jj]);
#pragma unroll
    for (int jj = 0; jj < 4; ++jj) load_lds16(gW[jj], &lB[0][0] + lq[jj]);

#pragma unroll
    for (int kt = 0; kt < nIter; ++kt) {
        const int cur = kt & 1;
        if (kt + 1 < nIter) {
#pragma unroll
            for (int jj = 0; jj < 4; ++jj)
                load_lds16(gA[jj] + (kt + 1) * 128, &lA[cur ^ 1][0] + lq[jj]);
#pragma unroll
            for (int jj = 0; jj < 4; ++jj)
                load_lds16(gW[jj] + (kt + 1) * 128, &lB[cur ^ 1][0] + lq[jj]);
            WAIT_VM(8);
        } else {
            WAIT_VM(0);
        }
        __builtin_amdgcn_s_barrier();

#pragma unroll
        for (int kk = 0; kk < 2; ++kk) {
            const int sw = ((kk * 4 + quad) ^ x7) * 16;
            int4v af[MT], bfr[NT];
#pragma unroll
            for (int mt = 0; mt < MT; ++mt)
                af[mt] = *(const int4v*)(&lA[cur][(arow0 + mt * 16) * 128 + sw]);
#pragma unroll
            for (int nt = 0; nt < NT; ++nt)
                bfr[nt] = *(const int4v*)(&lB[cur][(brow0 + nt * 16) * 128 + sw]);
#pragma unroll
            for (int mt = 0; mt < MT; ++mt)
#pragma unroll
                for (int nt = 0; nt < NT; ++nt)
                    acc[mt][nt] = __builtin_amdgcn_mfma_i32_16x16x64_i8(
                        af[mt], bfr[nt], acc[mt][nt], 0, 0, 0);
        }
        __builtin_amdgcn_s_barrier();
    }

    const int m0 = brow + wr * 64 + quad * 4;
    const int n0 = bcol + wc * 64 + l16;
#pragma unroll
    for (int mt = 0; mt < MT; ++mt)
#pragma unroll
        for (int nt = 0; nt < NT; ++nt) {
            const int n = n0 + nt * 16;
            const float bb = bias[n];
            const float dqn = dq[n];
#pragma unroll
            for (int i = 0; i < 4; ++i) {
                const int m = m0 + mt * 16 + i;
                const float t = fast_tanh((float)acc[mt][nt][i] * dqn + bb);
                out[(size_t)m * N + n] = (int8_t)__float2int_rn(t * 127.f);
            }
        }
}

// L3: RK4-fused i8 GEMM. A = x2i, W = per-row i8 W3, K=1024, N=512.
// MODE 0 (k1):   kacc = kv;     x0q = i8((hb + alpha*kv + te) / S)
// MODE 1 (k2/3): kacc += 2*kv;  x0q likewise
// MODE 2 (k4):   hn = h + dt6*(kacc + kv); h_out=hn; hb_out=bf16(hn);
//                if (HASX0) { x0q = i8((hn + te)/S); atomicMax pend |hn| }
// All modes with x0: publish S in slots[2]. S = slots[0] (hmax_cur) + 1.0.
template <int MODE, bool HASX0>
__global__ void __launch_bounds__(256, 2)
gemm_k(const int8_t* __restrict__ A, const int8_t* __restrict__ W,
       const float* __restrict__ dq, const float* __restrict__ bias,
       bf16* __restrict__ kacc, const bf16* __restrict__ hb_src,
       const float* __restrict__ h_src, float* __restrict__ h_out,
       bf16* __restrict__ hb_out, int8_t* __restrict__ x0_out,
       const float* __restrict__ temb, float alpha, float dt6,
       float* __restrict__ slots) {
    constexpr int MT = 4, NT = 2, K = 1024;
    constexpr int nIter = K / 128;
    __shared__ alignas(16) int8_t lA[2][128 * 128];   // 2 x 16 KB
    __shared__ alignas(16) int8_t lB[2][64 * 128];    // 2 x  8 KB

    const int b   = blockIdx.x + gridDim.x * blockIdx.y;   // grid (8, 64)
    const int xcd = b & 7, j = b >> 3;
    const int bx  = j & 7;                                  // 8 N-tiles
    const int by  = xcd + 8 * (j >> 3);                     // 64 M-tiles

    const int tid  = threadIdx.x;
    const float S    = slots[0] + 1.0f;    // covers |h|+|a*kv|+|te|+drift
    const float invS = 127.f / S;
    if (HASX0 && b == 0 && tid == 0) slots[2] = S;

    const int lane = tid & 63;
    const int w    = tid >> 6;
    const int wr   = w >> 1, wc = w & 1;
    const int quad = lane >> 4, l16 = lane & 15;
    const int brow = by * 128;
    const int bcol = bx * 64;

    const int8_t* gA[4]; int lqA[4];
    const int8_t* gW[2]; int lqB[2];
#pragma unroll
    for (int jj = 0; jj < 4; ++jj) {
        const int q = tid + jj * 256;
        const int r = q >> 3, s = (q & 7) ^ (r & 7);
        gA[jj]  = A + (size_t)(brow + r) * K + s * 16;
        lqA[jj] = q * 16;
    }
#pragma unroll
    for (int jj = 0; jj < 2; ++jj) {
        const int q = tid + jj * 256;
        const int r = q >> 3, s = (q & 7) ^ (r & 7);
        gW[jj]  = W + (size_t)(bcol + r) * K + s * 16;
        lqB[jj] = q * 16;
    }

    int4v acc[MT][NT];
    const int4v izero = {0, 0, 0, 0};
#pragma unroll
    for (int mt = 0; mt < MT; ++mt)
#pragma unroll
        for (int nt = 0; nt < NT; ++nt) acc[mt][nt] = izero;

    const int arow0 = wr * 64 + l16;
    const int brow0 = wc * 32 + l16;
    const int x7 = l16 & 7;

#pragma unroll
    for (int jj = 0; jj < 4; ++jj) load_lds16(gA[jj], &lA[0][0] + lqA[jj]);
#pragma unroll
    for (int jj = 0; jj < 2; ++jj) load_lds16(gW[jj], &lB[0][0] + lqB[jj]);

#pragma unroll
    for (int kt = 0; kt < nIter; ++kt) {
        const int cur = kt & 1;
        if (kt + 1 < nIter) {
#pragma unroll
            for (int jj = 0; jj < 4; ++jj)
                load_lds16(gA[jj] + (kt + 1) * 128, &lA[cur ^ 1][0] + lqA[jj]);
#pragma unroll
            for (int jj = 0; jj < 2; ++jj)
                load_lds16(gW[jj] + (kt + 1) * 128, &lB[cur ^ 1][0] + lqB[jj]);
            WAIT_VM(6);
        } else {
            WAIT_VM(0);
        }
        __builtin_amdgcn_s_barrier();

#pragma unroll
        for (int kk = 0; kk < 2; ++kk) {
            const int sw = ((kk * 4 + quad) ^ x7) * 16;
            int4v af[MT], bfr[NT];
#pragma unroll
            for (int mt = 0; mt < MT; ++mt)
                af[mt] = *(const int4v*)(&lA[cur][(arow0 + mt * 16) * 128 + sw]);
#pragma unroll
            for (int nt = 0; nt < NT; ++nt)
                bfr[nt] = *(const int4v*)(&lB[cur][(brow0 + nt * 16) * 128 + sw]);
#pragma unroll
            for (int mt = 0; mt < MT; ++mt)
#pragma unroll
                for (int nt = 0; nt < NT; ++nt)
                    acc[mt][nt] = __builtin_amdgcn_mfma_i32_16x16x64_i8(
                        af[mt], bfr[nt], acc[mt][nt], 0, 0, 0);
        }
        __builtin_amdgcn_s_barrier();
    }

    const int m0 = brow + wr * 64 + quad * 4;
    const int n0 = bcol + wc * 32 + l16;
    float hmx = 0.f;   // per-thread |hn| max (MODE 2)
#pragma unroll
    for (int mt = 0; mt < MT; ++mt)
#pragma unroll
        for (int nt = 0; nt < NT; ++nt) {
            const int n = n0 + nt * 16;
            const float bb = bias[n];
            const float dqn = dq[n];
            const float te = temb[n];
#pragma unroll
            for (int i = 0; i < 4; ++i) {
                const int m = m0 + mt * 16 + i;
                const size_t idx = (size_t)m * 512 + n;
                const float kv = (float)acc[mt][nt][i] * dqn + bb;
                if constexpr (MODE == 0) {
                    kacc[idx] = __float2bfloat16(kv);
                    x0_out[idx] = q_i8(
                        __bfloat162float(hb_src[idx]) + alpha * kv + te, invS);
                } else if constexpr (MODE == 1) {
                    kacc[idx] = __float2bfloat16(__bfloat162float(kacc[idx]) + 2.f * kv);
                    x0_out[idx] = q_i8(
                        __bfloat162float(hb_src[idx]) + alpha * kv + te, invS);
                } else {
                    const float hn = h_src[idx] + dt6 * (__bfloat162float(kacc[idx]) + kv);
                    h_out[idx] = hn;
                    hb_out[idx] = __float2bfloat16(hn);
                    if constexpr (HASX0) {
                        x0_out[idx] = q_i8(hn + te, invS);
                        hmx = fmaxf(hmx, fabsf(hn));
                    }
                }
            }
        }
    if constexpr (MODE == 2 && HASX0) {
        // wave reduce then one atomic per wave into the pending hmax slot
#pragma unroll
        for (int off = 32; off > 0; off >>= 1)
            hmx = fmaxf(hmx, __shfl_down(hmx, off));
        if (lane == 0) atomicMaxPosF(&slots[1], hmx);
    }
}

// ---------------------------------------------------------------------------
// Prep kernels.
// ---------------------------------------------------------------------------

__global__ void init_slots(float* __restrict__ slots) {
    slots[0] = 0.f; slots[1] = 0.f; slots[2] = 1.f;
}

// slots[0] = max|h_in| (grid-stride, wave-reduced atomics)
__global__ void hmax_kern(const float* __restrict__ h, int total,
                          float* __restrict__ slots) {
    const int stride = gridDim.x * blockDim.x;
    float m = 0.f;
    for (int i = blockIdx.x * blockDim.x + threadIdx.x; i < total; i += stride)
        m = fmaxf(m, fabsf(h[i]));
#pragma unroll
    for (int off = 32; off > 0; off >>= 1)
        m = fmaxf(m, __shfl_down(m, off));
    if ((threadIdx.x & 63) == 0) atomicMaxPosF(&slots[0], m);
}

// Per-row i8 quantization (rows = gridDim.x, length K): dq[n] = rmax/127^2.
__global__ void quantW_row(const float* __restrict__ W, int K,
                           int8_t* __restrict__ out, float* __restrict__ dq) {
    __shared__ float red[256];
    const int row = blockIdx.x, tid = threadIdx.x;
    const float* src = W + (size_t)row * K;
    float m = 0.f;
    for (int k = tid; k < K; k += 256) m = fmaxf(m, fabsf(src[k]));
    red[tid] = m;
    __syncthreads();
    for (int s = 128; s > 0; s >>= 1) {
        if (tid < s) red[tid] = fmaxf(red[tid], red[tid + s]);
        __syncthreads();
    }
    const float rmax = fmaxf(red[0], 1e-8f);
    const float sc = 127.f / rmax;
    int8_t* dst = out + (size_t)row * K;
    for (int k = tid; k < K; k += 256) {
        int v = __float2int_rn(src[k] * sc);
        v = v > 127 ? 127 : (v < -127 ? -127 : v);
        dst[k] = (int8_t)v;
    }
    if (tid == 0) dq[row] = rmax / (127.f * 127.f);
}

// Fused prep: x0q = i8((h + bt[n]) / S0), hb = bf16(h), temb table,
// S0 = hmax_in + 0.4 (covers |bt|max). Publishes S0, seeds slots.
__global__ void prep_kern(const float* __restrict__ h, const float* __restrict__ bt,
                          const float* __restrict__ Wt, float* __restrict__ temb,
                          int8_t* __restrict__ x0q, bf16* __restrict__ hb,
                          float half_dt, int total, float* __restrict__ slots) {
    const int i = blockIdx.x * blockDim.x + threadIdx.x;
    const float S0 = slots[0] + 0.4f;
    if (i == 0) { slots[2] = S0; slots[1] = 0.f; }
    const float invS = 127.f / S0;
    if (i < total) {
        const float hv = h[i];
        x0q[i] = q_i8(hv + bt[i & 511], invS);
        hb[i] = __float2bfloat16(hv);
    }
    if (i < 21 * 512) {
        const int jj = i >> 9, n = i & 511;
        temb[i] = (jj * half_dt) * Wt[n] + bt[n];
    }
}

extern "C" void kernel_launch(void* const* d_in, const int* in_sizes, int n_in,
                              void* d_out, int out_size, void* d_ws, size_t ws_size,
                              hipStream_t stream) {
    const float* h_in = (const float*)d_in[0];
    const float* W1 = (const float*)d_in[1];
    const float* b1 = (const float*)d_in[2];
    const float* W2 = (const float*)d_in[3];
    const float* b2 = (const float*)d_in[4];
    const float* W3 = (const float*)d_in[5];
    const float* b3 = (const float*)d_in[6];
    const float* Wt = (const float*)d_in[7];
    const float* bt = (const float*)d_in[8];
    // n_steps (d_in[9]) is a fixed Python scalar = 10.
    const int B = 8192, H = 512, H2 = 1024, NS = 10;
    const float dt = 1.f / NS;

    char* ws = (char*)d_ws;
    auto alloc = [&](size_t bytes) {
        char* p = ws;
        ws += (bytes + 255) & ~(size_t)255;
        return p;
    };
    int8_t* W1i = (int8_t*)alloc((size_t)H2 * H);       // i8 W1, per-row scaled
    float* dq1  = (float*)alloc((size_t)H2 * 4);
    int8_t* W2i = (int8_t*)alloc((size_t)H2 * H2);      // i8 W2
    float* dq2  = (float*)alloc((size_t)H2 * 4);
    int8_t* W3i = (int8_t*)alloc((size_t)H * H2);       // i8 W3
    float* dq3  = (float*)alloc((size_t)H * 4);
    int8_t* x0q = (int8_t*)alloc((size_t)B * H);        // i8 x0 (dyn scale)
    int8_t* x1i = (int8_t*)alloc((size_t)B * H2);       // i8 tanh1 * 127
    int8_t* x2i = (int8_t*)alloc((size_t)B * H2);       // i8 tanh2 * 127
    bf16* kacc = (bf16*)alloc((size_t)B * H * 2);
    bf16* hb   = (bf16*)alloc((size_t)B * H * 2);
    float* temb = (float*)alloc((size_t)21 * H * 4);
    float* slots = (float*)alloc(256);                  // hmax_cur/pend/xscale
    float* hbuf = (float*)d_out;  // h ping-pongs through d_out (fp32)

    {
        init_slots<<<1, 1, 0, stream>>>(slots);
        hmax_kern<<<1024, 256, 0, stream>>>(h_in, B * H, slots);
        quantW_row<<<H2, 256, 0, stream>>>(W1, H, W1i, dq1);
        quantW_row<<<H2, 256, 0, stream>>>(W2, H2, W2i, dq2);
        quantW_row<<<H, 256, 0, stream>>>(W3, H2, W3i, dq3);
    }
    {
        const int total = B * H;
        prep_kern<<<(total + 255) / 256, 256, 0, stream>>>(
            h_in, bt, Wt, temb, x0q, hb, dt * 0.5f, total, slots);
    }

    const dim3 blk256(256);
    const dim3 g12(H2 / 128, B / 128);  // 8 x 64 = 512 blocks (2/CU)
    const dim3 g3(H / 64, B / 128);     // 8 x 64 = 512 blocks (2/CU), 128x64

    for (int s = 0; s < NS; ++s) {
        const float* hs = (s == 0) ? h_in : hbuf;
        const float* tmid = temb + (size_t)(2 * s + 1) * H;
        const float* tend = temb + (size_t)(2 * s + 2) * H;
        for (int e = 0; e < 4; ++e) {
            gemm_l1<512, 1024><<<g12, blk256, 0, stream>>>(x0q, W1i, dq1, b1,
                                                           x1i, slots);
            gemm_tanh_i8<1024, 1024><<<g12, blk256, 0, stream>>>(x1i, W2i, dq2,
                                                                 b2, x2i);
            if (e == 0)
                gemm_k<0, true><<<g3, blk256, 0, stream>>>(
                    x2i, W3i, dq3, b3, kacc, hb, hs, nullptr, nullptr, x0q,
                    tmid, dt * 0.5f, 0.f, slots);
            else if (e == 1)
                gemm_k<1, true><<<g3, blk256, 0, stream>>>(
                    x2i, W3i, dq3, b3, kacc, hb, hs, nullptr, nullptr, x0q,
                    tmid, dt * 0.5f, 0.f, slots);
            else if (e == 2)
                gemm_k<1, true><<<g3, blk256, 0, stream>>>(
                    x2i, W3i, dq3, b3, kacc, hb, hs, nullptr, nullptr, x0q,
                    tend, dt, 0.f, slots);
            else if (s != NS - 1)
                gemm_k<2, true><<<g3, blk256, 0, stream>>>(
                    x2i, W3i, dq3, b3, kacc, hb, hs, hbuf, hb, x0q,
                    tend, 0.f, dt / 6.f, slots);
            else
                gemm_k<2, false><<<g3, blk256, 0, stream>>>(
                    x2i, W3i, dq3, b3, kacc, hb, hs, hbuf, hb, nullptr,
                    tend, 0.f, dt / 6.f, slots);
        }
    }
}

// Round 15
// 1685.473 us; speedup vs baseline: 1.1152x; 1.1152x over previous
//
#include <hip/hip_runtime.h>
#include <hip/hip_bf16.h>
#include <math.h>
#include <stdint.h>

using bf16 = __hip_bfloat16;
typedef __attribute__((ext_vector_type(8))) short short8;   // 8 bf16
typedef __attribute__((ext_vector_type(4))) float floatx4;  // MFMA C/D frag (f32)
typedef __attribute__((ext_vector_type(4))) int int4v;      // i8 K=64 frag / i32 acc

typedef const __attribute__((address_space(1))) void* gptr_t;
typedef __attribute__((address_space(3))) void* lptr_t;

__device__ __forceinline__ void load_lds16(const void* g, void* l) {
    __builtin_amdgcn_global_load_lds((gptr_t)(uintptr_t)g, (lptr_t)(uintptr_t)l, 16, 0, 0);
}

// wait until at most N vector-memory ops outstanding. gfx9 vmcnt 6 bits:
// lo[3:0]=bits3:0, hi[5:4]=bits15:14; lgkm/exp left at max (no wait).
#define WAIT_VM(n) __builtin_amdgcn_s_waitcnt(0x0F70 | ((n) & 15) | (((n) >> 4) << 14))

// tanh(x) = 1 - 2/(exp(2x)+1)
__device__ __forceinline__ float fast_tanh(float x) {
    float e = __expf(2.f * x);
    return 1.f - 2.f / (e + 1.f);
}

__device__ __forceinline__ int8_t q_i8(float x, float inv127S) {
    int v = __float2int_rn(x * inv127S);
    v = v > 127 ? 127 : (v < -127 ? -127 : v);
    return (int8_t)v;
}

// device-scope atomic max for positive floats (int ordering preserves)
__device__ __forceinline__ void atomicMaxPosF(float* p, float v) {
    atomicMax(reinterpret_cast<int*>(p), __float_as_int(v));
}

// ---------------------------------------------------------------------------
// R15 = R14 (1880us, absmax 0.094 — i8 L1 itself saved ~110us) minus the
// atomic storms the counters convicted:
//  - hmax_kern was 52us/replay: 4096 same-address device atomics @ ~12ns
//    serialize (reads are only ~3us of BW). Fix: block-reduce + CHECK-THEN-
//    ATOMIC (read slot, only atomicMax if larger) -> ~O(10) atomics, ~5us.
//  - gemm_k<2,true> tail: 2048 atomics/dispatch (~25us) x 9. Fix: wave-shfl
//    -> 4-slot scratch in dead lA LDS -> block max -> check-then-atomic.
// Max is exact under any reduction order -> S values and results are
// bit-identical to R14: absmax exactly 0.09375.
// slots[0]=hmax_cur, slots[1]=hmax_pend, slots[2]=xscale.
// ---------------------------------------------------------------------------

// L1: x1q = i8(tanh(acc*dq1[n]*S + b1)*127), i8 core. K=512, N=1024.
template <int K, int N>
__global__ void __launch_bounds__(256, 2)
gemm_l1(const int8_t* __restrict__ A, const int8_t* __restrict__ W,
        const float* __restrict__ dq, const float* __restrict__ bias,
        int8_t* __restrict__ out, float* __restrict__ slots) {
    constexpr int MT = 4, NT = 4;
    constexpr int nIter = K / 128;   // 4
    __shared__ alignas(16) int8_t lA[2][128 * 128];
    __shared__ alignas(16) int8_t lB[2][128 * 128];

    const int b   = blockIdx.x + gridDim.x * blockIdx.y;   // grid (8, 64)
    const int xcd = b & 7, j = b >> 3;
    const int bx  = j & 7;
    const int by  = xcd + 8 * (j >> 3);

    const int tid  = threadIdx.x;

    // commit pending hmax (written by the previous mode-2 dispatch) for this
    // step's gemm_k dispatches. Only slots[0]/[1] touched; no L1 block reads
    // them, so no intra-dispatch race.
    if (b == 0 && tid == 0) {
        const float p = slots[1];
        if (p > 0.f) { slots[0] = p; slots[1] = 0.f; }
    }
    const float xs = slots[2];   // scale used by this x0's writer

    const int lane = tid & 63;
    const int w    = tid >> 6;
    const int wr   = w >> 1, wc = w & 1;
    const int quad = lane >> 4, l16 = lane & 15;
    const int brow = by * 128;
    const int bcol = bx * 128;

    const int8_t* gA[4]; const int8_t* gW[4]; int lq[4];
#pragma unroll
    for (int jj = 0; jj < 4; ++jj) {
        const int q = tid + jj * 256;
        const int r = q >> 3, s = (q & 7) ^ (r & 7);
        gA[jj] = A + (size_t)(brow + r) * K + s * 16;
        gW[jj] = W + (size_t)(bcol + r) * K + s * 16;
        lq[jj] = q * 16;
    }

    int4v acc[MT][NT];
    const int4v izero = {0, 0, 0, 0};
#pragma unroll
    for (int mt = 0; mt < MT; ++mt)
#pragma unroll
        for (int nt = 0; nt < NT; ++nt) acc[mt][nt] = izero;

    const int arow0 = wr * 64 + l16;
    const int brow0 = wc * 64 + l16;
    const int x7 = l16 & 7;

#pragma unroll
    for (int jj = 0; jj < 4; ++jj) load_lds16(gA[jj], &lA[0][0] + lq[jj]);
#pragma unroll
    for (int jj = 0; jj < 4; ++jj) load_lds16(gW[jj], &lB[0][0] + lq[jj]);

#pragma unroll
    for (int kt = 0; kt < nIter; ++kt) {
        const int cur = kt & 1;
        if (kt + 1 < nIter) {
#pragma unroll
            for (int jj = 0; jj < 4; ++jj)
                load_lds16(gA[jj] + (kt + 1) * 128, &lA[cur ^ 1][0] + lq[jj]);
#pragma unroll
            for (int jj = 0; jj < 4; ++jj)
                load_lds16(gW[jj] + (kt + 1) * 128, &lB[cur ^ 1][0] + lq[jj]);
            WAIT_VM(8);
        } else {
            WAIT_VM(0);
        }
        __builtin_amdgcn_s_barrier();

#pragma unroll
        for (int kk = 0; kk < 2; ++kk) {
            const int sw = ((kk * 4 + quad) ^ x7) * 16;
            int4v af[MT], bfr[NT];
#pragma unroll
            for (int mt = 0; mt < MT; ++mt)
                af[mt] = *(const int4v*)(&lA[cur][(arow0 + mt * 16) * 128 + sw]);
#pragma unroll
            for (int nt = 0; nt < NT; ++nt)
                bfr[nt] = *(const int4v*)(&lB[cur][(brow0 + nt * 16) * 128 + sw]);
#pragma unroll
            for (int mt = 0; mt < MT; ++mt)
#pragma unroll
                for (int nt = 0; nt < NT; ++nt)
                    acc[mt][nt] = __builtin_amdgcn_mfma_i32_16x16x64_i8(
                        af[mt], bfr[nt], acc[mt][nt], 0, 0, 0);
        }
        __builtin_amdgcn_s_barrier();
    }

    const int m0 = brow + wr * 64 + quad * 4;
    const int n0 = bcol + wc * 64 + l16;
#pragma unroll
    for (int mt = 0; mt < MT; ++mt)
#pragma unroll
        for (int nt = 0; nt < NT; ++nt) {
            const int n = n0 + nt * 16;
            const float bb = bias[n];
            const float dqs = dq[n] * xs;
#pragma unroll
            for (int i = 0; i < 4; ++i) {
                const int m = m0 + mt * 16 + i;
                const float t = fast_tanh((float)acc[mt][nt][i] * dqs + bb);
                out[(size_t)m * N + n] = (int8_t)__float2int_rn(t * 127.f);
            }
        }
}

// L2: x2i = i8(tanh(acc*dq[n] + b2)*127), i8 core. 128x128, dbuf, 2 blk/CU.
template <int K, int N>
__global__ void __launch_bounds__(256, 2)
gemm_tanh_i8(const int8_t* __restrict__ A, const int8_t* __restrict__ W,
             const float* __restrict__ dq, const float* __restrict__ bias,
             int8_t* __restrict__ out) {
    constexpr int MT = 4, NT = 4;
    constexpr int nIter = K / 128;
    __shared__ alignas(16) int8_t lA[2][128 * 128];
    __shared__ alignas(16) int8_t lB[2][128 * 128];

    const int b   = blockIdx.x + gridDim.x * blockIdx.y;   // grid (8, 64)
    const int xcd = b & 7, j = b >> 3;
    const int bx  = j & 7;
    const int by  = xcd + 8 * (j >> 3);

    const int tid  = threadIdx.x;
    const int lane = tid & 63;
    const int w    = tid >> 6;
    const int wr   = w >> 1, wc = w & 1;
    const int quad = lane >> 4, l16 = lane & 15;
    const int brow = by * 128;
    const int bcol = bx * 128;

    const int8_t* gA[4]; const int8_t* gW[4]; int lq[4];
#pragma unroll
    for (int jj = 0; jj < 4; ++jj) {
        const int q = tid + jj * 256;
        const int r = q >> 3, s = (q & 7) ^ (r & 7);
        gA[jj] = A + (size_t)(brow + r) * K + s * 16;
        gW[jj] = W + (size_t)(bcol + r) * K + s * 16;
        lq[jj] = q * 16;
    }

    int4v acc[MT][NT];
    const int4v izero = {0, 0, 0, 0};
#pragma unroll
    for (int mt = 0; mt < MT; ++mt)
#pragma unroll
        for (int nt = 0; nt < NT; ++nt) acc[mt][nt] = izero;

    const int arow0 = wr * 64 + l16;
    const int brow0 = wc * 64 + l16;
    const int x7 = l16 & 7;

#pragma unroll
    for (int jj = 0; jj < 4; ++jj) load_lds16(gA[jj], &lA[0][0] + lq[jj]);
#pragma unroll
    for (int jj = 0; jj < 4; ++jj) load_lds16(gW[jj], &lB[0][0] + lq[jj]);

#pragma unroll
    for (int kt = 0; kt < nIter; ++kt) {
        const int cur = kt & 1;
        if (kt + 1 < nIter) {
#pragma unroll
            for (int jj = 0; jj < 4; ++jj)
                load_lds16(gA[jj] + (kt + 1) * 128, &lA[cur ^ 1][0] + lq[jj]);
#pragma unroll
            for (int jj = 0; jj < 4; ++jj)
                load_lds16(gW[jj] + (kt + 1) * 128, &lB[cur ^ 1][0] + lq[jj]);
            WAIT_VM(8);
        } else {
            WAIT_VM(0);
        }
        __builtin_amdgcn_s_barrier();

#pragma unroll
        for (int kk = 0; kk < 2; ++kk) {
            const int sw = ((kk * 4 + quad) ^ x7) * 16;
            int4v af[MT], bfr[NT];
#pragma unroll
            for (int mt = 0; mt < MT; ++mt)
                af[mt] = *(const int4v*)(&lA[cur][(arow0 + mt * 16) * 128 + sw]);
#pragma unroll
            for (int nt = 0; nt < NT; ++nt)
                bfr[nt] = *(const int4v*)(&lB[cur][(brow0 + nt * 16) * 128 + sw]);
#pragma unroll
            for (int mt = 0; mt < MT; ++mt)
#pragma unroll
                for (int nt = 0; nt < NT; ++nt)
                    acc[mt][nt] = __builtin_amdgcn_mfma_i32_16x16x64_i8(
                        af[mt], bfr[nt], acc[mt][nt], 0, 0, 0);
        }
        __builtin_amdgcn_s_barrier();
    }

    const int m0 = brow + wr * 64 + quad * 4;
    const int n0 = bcol + wc * 64 + l16;
#pragma unroll
    for (int mt = 0; mt < MT; ++mt)
#pragma unroll
        for (int nt = 0; nt < NT; ++nt) {
            const int n = n0 + nt * 16;
            const float bb = bias[n];
            const float dqn = dq[n];
#pragma unroll
            for (int i = 0; i < 4; ++i) {
                const int m = m0 + mt * 16 + i;
                const float t = fast_tanh((float)acc[mt][nt][i] * dqn + bb);
                out[(size_t)m * N + n] = (int8_t)__float2int_rn(t * 127.f);
            }
        }
}

// L3: RK4-fused i8 GEMM. A = x2i, W = per-row i8 W3, K=1024, N=512.
// MODE 0 (k1):   kacc = kv;     x0q = i8((hb + alpha*kv + te) / S)
// MODE 1 (k2/3): kacc += 2*kv;  x0q likewise
// MODE 2 (k4):   hn = h + dt6*(kacc + kv); h_out=hn; hb_out=bf16(hn);
//                if (HASX0) { x0q = i8((hn + te)/S); track |hn| block max }
// All modes with x0: publish S in slots[2]. S = slots[0] (hmax_cur) + 1.0.
template <int MODE, bool HASX0>
__global__ void __launch_bounds__(256, 2)
gemm_k(const int8_t* __restrict__ A, const int8_t* __restrict__ W,
       const float* __restrict__ dq, const float* __restrict__ bias,
       bf16* __restrict__ kacc, const bf16* __restrict__ hb_src,
       const float* __restrict__ h_src, float* __restrict__ h_out,
       bf16* __restrict__ hb_out, int8_t* __restrict__ x0_out,
       const float* __restrict__ temb, float alpha, float dt6,
       float* __restrict__ slots) {
    constexpr int MT = 4, NT = 2, K = 1024;
    constexpr int nIter = K / 128;
    __shared__ alignas(16) int8_t lA[2][128 * 128];   // 2 x 16 KB
    __shared__ alignas(16) int8_t lB[2][64 * 128];    // 2 x  8 KB

    const int b   = blockIdx.x + gridDim.x * blockIdx.y;   // grid (8, 64)
    const int xcd = b & 7, j = b >> 3;
    const int bx  = j & 7;                                  // 8 N-tiles
    const int by  = xcd + 8 * (j >> 3);                     // 64 M-tiles

    const int tid  = threadIdx.x;
    const float S    = slots[0] + 1.0f;    // covers |h|+|a*kv|+|te|+drift
    const float invS = 127.f / S;
    if (HASX0 && b == 0 && tid == 0) slots[2] = S;

    const int lane = tid & 63;
    const int w    = tid >> 6;
    const int wr   = w >> 1, wc = w & 1;
    const int quad = lane >> 4, l16 = lane & 15;
    const int brow = by * 128;
    const int bcol = bx * 64;

    const int8_t* gA[4]; int lqA[4];
    const int8_t* gW[2]; int lqB[2];
#pragma unroll
    for (int jj = 0; jj < 4; ++jj) {
        const int q = tid + jj * 256;
        const int r = q >> 3, s = (q & 7) ^ (r & 7);
        gA[jj]  = A + (size_t)(brow + r) * K + s * 16;
        lqA[jj] = q * 16;
    }
#pragma unroll
    for (int jj = 0; jj < 2; ++jj) {
        const int q = tid + jj * 256;
        const int r = q >> 3, s = (q & 7) ^ (r & 7);
        gW[jj]  = W + (size_t)(bcol + r) * K + s * 16;
        lqB[jj] = q * 16;
    }

    int4v acc[MT][NT];
    const int4v izero = {0, 0, 0, 0};
#pragma unroll
    for (int mt = 0; mt < MT; ++mt)
#pragma unroll
        for (int nt = 0; nt < NT; ++nt) acc[mt][nt] = izero;

    const int arow0 = wr * 64 + l16;
    const int brow0 = wc * 32 + l16;
    const int x7 = l16 & 7;

#pragma unroll
    for (int jj = 0; jj < 4; ++jj) load_lds16(gA[jj], &lA[0][0] + lqA[jj]);
#pragma unroll
    for (int jj = 0; jj < 2; ++jj) load_lds16(gW[jj], &lB[0][0] + lqB[jj]);

#pragma unroll
    for (int kt = 0; kt < nIter; ++kt) {
        const int cur = kt & 1;
        if (kt + 1 < nIter) {
#pragma unroll
            for (int jj = 0; jj < 4; ++jj)
                load_lds16(gA[jj] + (kt + 1) * 128, &lA[cur ^ 1][0] + lqA[jj]);
#pragma unroll
            for (int jj = 0; jj < 2; ++jj)
                load_lds16(gW[jj] + (kt + 1) * 128, &lB[cur ^ 1][0] + lqB[jj]);
            WAIT_VM(6);
        } else {
            WAIT_VM(0);
        }
        __builtin_amdgcn_s_barrier();

#pragma unroll
        for (int kk = 0; kk < 2; ++kk) {
            const int sw = ((kk * 4 + quad) ^ x7) * 16;
            int4v af[MT], bfr[NT];
#pragma unroll
            for (int mt = 0; mt < MT; ++mt)
                af[mt] = *(const int4v*)(&lA[cur][(arow0 + mt * 16) * 128 + sw]);
#pragma unroll
            for (int nt = 0; nt < NT; ++nt)
                bfr[nt] = *(const int4v*)(&lB[cur][(brow0 + nt * 16) * 128 + sw]);
#pragma unroll
            for (int mt = 0; mt < MT; ++mt)
#pragma unroll
                for (int nt = 0; nt < NT; ++nt)
                    acc[mt][nt] = __builtin_amdgcn_mfma_i32_16x16x64_i8(
                        af[mt], bfr[nt], acc[mt][nt], 0, 0, 0);
        }
        __builtin_amdgcn_s_barrier();
    }

    const int m0 = brow + wr * 64 + quad * 4;
    const int n0 = bcol + wc * 32 + l16;
    float hmx = 0.f;   // per-thread |hn| max (MODE 2)
#pragma unroll
    for (int mt = 0; mt < MT; ++mt)
#pragma unroll
        for (int nt = 0; nt < NT; ++nt) {
            const int n = n0 + nt * 16;
            const float bb = bias[n];
            const float dqn = dq[n];
            const float te = temb[n];
#pragma unroll
            for (int i = 0; i < 4; ++i) {
                const int m = m0 + mt * 16 + i;
                const size_t idx = (size_t)m * 512 + n;
                const float kv = (float)acc[mt][nt][i] * dqn + bb;
                if constexpr (MODE == 0) {
                    kacc[idx] = __float2bfloat16(kv);
                    x0_out[idx] = q_i8(
                        __bfloat162float(hb_src[idx]) + alpha * kv + te, invS);
                } else if constexpr (MODE == 1) {
                    kacc[idx] = __float2bfloat16(__bfloat162float(kacc[idx]) + 2.f * kv);
                    x0_out[idx] = q_i8(
                        __bfloat162float(hb_src[idx]) + alpha * kv + te, invS);
                } else {
                    const float hn = h_src[idx] + dt6 * (__bfloat162float(kacc[idx]) + kv);
                    h_out[idx] = hn;
                    hb_out[idx] = __float2bfloat16(hn);
                    if constexpr (HASX0) {
                        x0_out[idx] = q_i8(hn + te, invS);
                        hmx = fmaxf(hmx, fabsf(hn));
                    }
                }
            }
        }
    if constexpr (MODE == 2 && HASX0) {
        // wave shfl reduce -> 4-slot scratch in dead lA LDS -> block max ->
        // check-then-atomic (only blocks beating the current pend issue one).
#pragma unroll
        for (int off = 32; off > 0; off >>= 1)
            hmx = fmaxf(hmx, __shfl_down(hmx, off));
        float* red = (float*)&lA[0][0];   // K-loop LDS is dead here
        __syncthreads();
        if (lane == 0) red[w] = hmx;
        __syncthreads();
        if (tid == 0) {
            const float bm = fmaxf(fmaxf(red[0], red[1]), fmaxf(red[2], red[3]));
            if (bm > slots[1]) atomicMaxPosF(&slots[1], bm);
        }
    }
}

// ---------------------------------------------------------------------------
// Prep kernels.
// ---------------------------------------------------------------------------

__global__ void init_slots(float* __restrict__ slots) {
    slots[0] = 0.f; slots[1] = 0.f; slots[2] = 1.f;
}

// slots[0] = max|h_in|. 256 blocks x 256 thr, float4 loads, block-reduce,
// check-then-atomic (~O(10) atomics instead of 4096).
__global__ void hmax_kern(const float* __restrict__ h, int total4,
                          float* __restrict__ slots) {
    __shared__ float red[4];
    const float4* h4 = (const float4*)h;
    const int stride = gridDim.x * blockDim.x;
    float m = 0.f;
    for (int i = blockIdx.x * blockDim.x + threadIdx.x; i < total4; i += stride) {
        const float4 v = h4[i];
        m = fmaxf(fmaxf(fabsf(v.x), fabsf(v.y)), fmaxf(fabsf(v.z), fabsf(v.w)));
        m = fmaxf(m, m);  // no-op keep
        red[0] = red[0];  // placate nothing
        break;            // replaced below
    }
    // (re-done properly below; the loop above is not used)
    m = 0.f;
    for (int i = blockIdx.x * blockDim.x + threadIdx.x; i < total4; i += stride) {
        const float4 v = h4[i];
        m = fmaxf(m, fmaxf(fmaxf(fabsf(v.x), fabsf(v.y)),
                           fmaxf(fabsf(v.z), fabsf(v.w))));
    }
#pragma unroll
    for (int off = 32; off > 0; off >>= 1)
        m = fmaxf(m, __shfl_down(m, off));
    const int lane = threadIdx.x & 63, w = threadIdx.x >> 6;
    if (lane == 0) red[w] = m;
    __syncthreads();
    if (threadIdx.x == 0) {
        const float bm = fmaxf(fmaxf(red[0], red[1]), fmaxf(red[2], red[3]));
        if (bm > slots[0]) atomicMaxPosF(&slots[0], bm);
    }
}

// Per-row i8 quantization (rows = gridDim.x, length K): dq[n] = rmax/127^2.
__global__ void quantW_row(const float* __restrict__ W, int K,
                           int8_t* __restrict__ out, float* __restrict__ dq) {
    __shared__ float red[256];
    const int row = blockIdx.x, tid = threadIdx.x;
    const float* src = W + (size_t)row * K;
    float m = 0.f;
    for (int k = tid; k < K; k += 256) m = fmaxf(m, fabsf(src[k]));
    red[tid] = m;
    __syncthreads();
    for (int s = 128; s > 0; s >>= 1) {
        if (tid < s) red[tid] = fmaxf(red[tid], red[tid + s]);
        __syncthreads();
    }
    const float rmax = fmaxf(red[0], 1e-8f);
    const float sc = 127.f / rmax;
    int8_t* dst = out + (size_t)row * K;
    for (int k = tid; k < K; k += 256) {
        int v = __float2int_rn(src[k] * sc);
        v = v > 127 ? 127 : (v < -127 ? -127 : v);
        dst[k] = (int8_t)v;
    }
    if (tid == 0) dq[row] = rmax / (127.f * 127.f);
}

// Fused prep: x0q = i8((h + bt[n]) / S0), hb = bf16(h), temb table,
// S0 = hmax_in + 0.4 (covers |bt|max). Publishes S0, seeds slots.
__global__ void prep_kern(const float* __restrict__ h, const float* __restrict__ bt,
                          const float* __restrict__ Wt, float* __restrict__ temb,
                          int8_t* __restrict__ x0q, bf16* __restrict__ hb,
                          float half_dt, int total, float* __restrict__ slots) {
    const int i = blockIdx.x * blockDim.x + threadIdx.x;
    const float S0 = slots[0] + 0.4f;
    if (i == 0) { slots[2] = S0; slots[1] = 0.f; }
    const float invS = 127.f / S0;
    if (i < total) {
        const float hv = h[i];
        x0q[i] = q_i8(hv + bt[i & 511], invS);
        hb[i] = __float2bfloat16(hv);
    }
    if (i < 21 * 512) {
        const int jj = i >> 9, n = i & 511;
        temb[i] = (jj * half_dt) * Wt[n] + bt[n];
    }
}

extern "C" void kernel_launch(void* const* d_in, const int* in_sizes, int n_in,
                              void* d_out, int out_size, void* d_ws, size_t ws_size,
                              hipStream_t stream) {
    const float* h_in = (const float*)d_in[0];
    const float* W1 = (const float*)d_in[1];
    const float* b1 = (const float*)d_in[2];
    const float* W2 = (const float*)d_in[3];
    const float* b2 = (const float*)d_in[4];
    const float* W3 = (const float*)d_in[5];
    const float* b3 = (const float*)d_in[6];
    const float* Wt = (const float*)d_in[7];
    const float* bt = (const float*)d_in[8];
    // n_steps (d_in[9]) is a fixed Python scalar = 10.
    const int B = 8192, H = 512, H2 = 1024, NS = 10;
    const float dt = 1.f / NS;

    char* ws = (char*)d_ws;
    auto alloc = [&](size_t bytes) {
        char* p = ws;
        ws += (bytes + 255) & ~(size_t)255;
        return p;
    };
    int8_t* W1i = (int8_t*)alloc((size_t)H2 * H);       // i8 W1, per-row scaled
    float* dq1  = (float*)alloc((size_t)H2 * 4);
    int8_t* W2i = (int8_t*)alloc((size_t)H2 * H2);      // i8 W2
    float* dq2  = (float*)alloc((size_t)H2 * 4);
    int8_t* W3i = (int8_t*)alloc((size_t)H * H2);       // i8 W3
    float* dq3  = (float*)alloc((size_t)H * 4);
    int8_t* x0q = (int8_t*)alloc((size_t)B * H);        // i8 x0 (dyn scale)
    int8_t* x1i = (int8_t*)alloc((size_t)B * H2);       // i8 tanh1 * 127
    int8_t* x2i = (int8_t*)alloc((size_t)B * H2);       // i8 tanh2 * 127
    bf16* kacc = (bf16*)alloc((size_t)B * H * 2);
    bf16* hb   = (bf16*)alloc((size_t)B * H * 2);
    float* temb = (float*)alloc((size_t)21 * H * 4);
    float* slots = (float*)alloc(256);                  // hmax_cur/pend/xscale
    float* hbuf = (float*)d_out;  // h ping-pongs through d_out (fp32)

    {
        init_slots<<<1, 1, 0, stream>>>(slots);
        hmax_kern<<<256, 256, 0, stream>>>(h_in, (B * H) / 4, slots);
        quantW_row<<<H2, 256, 0, stream>>>(W1, H, W1i, dq1);
        quantW_row<<<H2, 256, 0, stream>>>(W2, H2, W2i, dq2);
        quantW_row<<<H, 256, 0, stream>>>(W3, H2, W3i, dq3);
    }
    {
        const int total = B * H;
        prep_kern<<<(total + 255) / 256, 256, 0, stream>>>(
            h_in, bt, Wt, temb, x0q, hb, dt * 0.5f, total, slots);
    }

    const dim3 blk256(256);
    const dim3 g12(H2 / 128, B / 128);  // 8 x 64 = 512 blocks (2/CU)
    const dim3 g3(H / 64, B / 128);     // 8 x 64 = 512 blocks (2/CU), 128x64

    for (int s = 0; s < NS; ++s) {
        const float* hs = (s == 0) ? h_in : hbuf;
        const float* tmid = temb + (size_t)(2 * s + 1) * H;
        const float* tend = temb + (size_t)(2 * s + 2) * H;
        for (int e = 0; e < 4; ++e) {
            gemm_l1<512, 1024><<<g12, blk256, 0, stream>>>(x0q, W1i, dq1, b1,
                                                           x1i, slots);
            gemm_tanh_i8<1024, 1024><<<g12, blk256, 0, stream>>>(x1i, W2i, dq2,
                                                                 b2, x2i);
            if (e == 0)
                gemm_k<0, true><<<g3, blk256, 0, stream>>>(
                    x2i, W3i, dq3, b3, kacc, hb, hs, nullptr, nullptr, x0q,
                    tmid, dt * 0.5f, 0.f, slots);
            else if (e == 1)
                gemm_k<1, true><<<g3, blk256, 0, stream>>>(
                    x2i, W3i, dq3, b3, kacc, hb, hs, nullptr, nullptr, x0q,
                    tmid, dt * 0.5f, 0.f, slots);
            else if (e == 2)
                gemm_k<1, true><<<g3, blk256, 0, stream>>>(
                    x2i, W3i, dq3, b3, kacc, hb, hs, nullptr, nullptr, x0q,
                    tend, dt, 0.f, slots);
            else if (s != NS - 1)
                gemm_k<2, true><<<g3, blk256, 0, stream>>>(
                    x2i, W3i, dq3, b3, kacc, hb, hs, hbuf, hb, x0q,
                    tend, 0.f, dt / 6.f, slots);
            else
                gemm_k<2, false><<<g3, blk256, 0, stream>>>(
                    x2i, W3i, dq3, b3, kacc, hb, hs, hbuf, hb, nullptr,
                    tend, 0.f, dt / 6.f, slots);
        }
    }
}